// Round 12
// baseline (126.914 us; speedup 1.0000x reference)
//
#include <hip/hip_runtime.h>
#include <math.h>

// FlowMatchingLoss: B=8, M=K=2048. Log-domain pre-scaled by log2e (hw exp2/log2).
//   K_log' = sc_b * c,  sc_b = -20*log2e/(cmax_b+1e-8)
// Round-12: 8 ROWS PER WAVE (256-thread blocks, 4 waves x 8 rows = 32 rows).
// Round-11 counters showed the inner loop is co-limited by the CU-shared LDS
// pipe (1 b128 + 1 b32 per wave-iter serving only 4 rows ~= 38us/CU across 12
// passes). Doubling rows/read halves LDS traffic; 8 independent exp2 chains
// keep ILP at the reduced 2 waves/SIMD. Same 64-blocks/batch barrier layout.
// Kept: fence-free L3-atomic routing, per-batch barriers, persistent scaled
// LDS points, folded sL staging, hoisted row constants, scalar fma chains.

#define LOG2E 1.4426950408889634f
#define TAU   0.95238095238095238f     // 1/(1+0.05)
#define NEG20LOG2E (-28.853900817779268f)

// workspace layout, 4-byte units
enum : int {
  OFF_LU    = 0,        // 16384: log_u * log2e   (L3-resident via atomics)
  OFF_LV    = 16384,    // 16384: log_v * log2e
  OFF_CPART = 32768,    // 512 per-block cmax partials (64/batch)
  OFF_SUMAP = 33280,    // 512 per-block sum(a) partials (64/batch)
  OFF_SWP   = 33792,    // 512 per-block sum(w)
  OFF_SEWP  = 34304,    // 512 per-block sum(w*err)
  OFF_FPART = 34816,    // 3*512 final partials (bce, sum_pi, sum_pi*klog)
  OFF_BBAR  = 36352,    // 8 batches x 512: [0..3]*32 arr | 4*32 root | (8+g)*32 rel
  OFF_GBAR  = 40448,    // global: 1024 arr | 32 root | 1024 rel
  OFF_END   = 42528
};

__device__ __forceinline__ float fexp2(float x){ return __builtin_amdgcn_exp2f(x); }
__device__ __forceinline__ float flog2(float x){ return __builtin_amdgcn_logf(x); }

// L3-coherent access (relaxed agent atomics: cache-bypass, no maintenance)
__device__ __forceinline__ float ld3(const float* p){
  return __hip_atomic_load(p, __ATOMIC_RELAXED, __HIP_MEMORY_SCOPE_AGENT);
}
__device__ __forceinline__ void st3(float* p, float v){
  __hip_atomic_store(p, v, __ATOMIC_RELAXED, __HIP_MEMORY_SCOPE_AGENT);
}

__device__ __forceinline__ float wave_sum(float v){
  #pragma unroll
  for(int m=32;m;m>>=1) v += __shfl_xor(v,m,64);
  return v;
}
__device__ __forceinline__ float wave_max(float v){
  #pragma unroll
  for(int m=32;m;m>>=1) v = fmaxf(v,__shfl_xor(v,m,64));
  return v;
}

// per-batch fence-free barrier: 64 blocks, 4 groups of 16 -> root ->
// 4 release flags; leaders spin on own group's flag (16 pollers/line).
__device__ __forceinline__ void bbar(unsigned* bbase, int phase, int blk){
  __syncthreads();
  if(threadIdx.x == 0){
    asm volatile("s_waitcnt vmcnt(0)" ::: "memory");   // stores reached L3
    const int g = (blk>>4)&3;
    unsigned* garr = bbase + g*32;
    unsigned* root = bbase + 4*32;
    unsigned* grel = bbase + (8+g)*32;
    const unsigned va = __hip_atomic_fetch_add(garr, 1u, __ATOMIC_RELAXED,
                                               __HIP_MEMORY_SCOPE_AGENT);
    if(va == (unsigned)(16*phase - 1)){
      const unsigned vr = __hip_atomic_fetch_add(root, 1u, __ATOMIC_RELAXED,
                                                 __HIP_MEMORY_SCOPE_AGENT);
      if(vr == (unsigned)(4*phase - 1)){
        #pragma unroll
        for(int g2=0; g2<4; ++g2)
          __hip_atomic_store(bbase + (8+g2)*32, (unsigned)phase,
                             __ATOMIC_RELAXED, __HIP_MEMORY_SCOPE_AGENT);
      }
    }
    while(__hip_atomic_load(grel, __ATOMIC_RELAXED, __HIP_MEMORY_SCOPE_AGENT)
          < (unsigned)phase)
      __builtin_amdgcn_s_sleep(1);
    asm volatile("" ::: "memory");
  }
  __syncthreads();
}

// one-shot global barrier (before combine): 32 groups of 16
__device__ __forceinline__ void gbar_all(unsigned* bar, int blk){
  __syncthreads();
  if(threadIdx.x == 0){
    asm volatile("s_waitcnt vmcnt(0)" ::: "memory");
    const int g = blk & 31;
    unsigned* garr = bar + g*32;
    unsigned* root = bar + 1024;
    unsigned* grel = bar + 1056 + g*32;
    const unsigned va = __hip_atomic_fetch_add(garr, 1u, __ATOMIC_RELAXED,
                                               __HIP_MEMORY_SCOPE_AGENT);
    if(va == 15u){
      const unsigned vr = __hip_atomic_fetch_add(root, 1u, __ATOMIC_RELAXED,
                                                 __HIP_MEMORY_SCOPE_AGENT);
      if(vr == 31u){
        #pragma unroll 8
        for(int g2=0; g2<32; ++g2)
          __hip_atomic_store(bar + 1056 + g2*32, 1u,
                             __ATOMIC_RELAXED, __HIP_MEMORY_SCOPE_AGENT);
      }
    }
    while(__hip_atomic_load(grel, __ATOMIC_RELAXED, __HIP_MEMORY_SCOPE_AGENT)
          < 1u)
      __builtin_amdgcn_s_sleep(1);
    asm volatile("" ::: "memory");
  }
  __syncthreads();
}

__global__ __launch_bounds__(256) void k_init(float* ws){
  unsigned* bar = reinterpret_cast<unsigned*>(ws);
  for(int i=threadIdx.x; i<OFF_END-OFF_BBAR; i+=256) bar[OFF_BBAR+i] = 0u;
}

// one lse half-iteration, 8 rows/wave. Points scaled in LDS
// (xyz = n2sc*xyz, w = sc*|.|^2); sL[k] = sc|pt_k|^2 + potential.
// Inner loop per row: 3 fma + exp2 + add. Row constant sc|A|^2 in epilogue.
#define LSE_PASS(ROWV, FIRSTV, PH) {                                          \
    const float4* sPT = ROWV ? sB : sA;                                       \
    float* lo = ws + (ROWV?OFF_LV:OFF_LU) + 2048*b;                           \
    float* op = ws + (ROWV?OFF_LU:OFF_LV);                                    \
    float4 A[8];                                                              \
    _Pragma("unroll")                                                         \
    for(int r=0;r<8;r++) A[r] = ROWV ? AR[r] : AC[r];                         \
    for(int i=tid;i<2048;i+=256)                                              \
      sL[i] = FIRSTV ? sPT[i].w : (ld3(lo+i) + sPT[i].w);                     \
    __syncthreads();                                                          \
    float s[8];                                                               \
    _Pragma("unroll")                                                         \
    for(int r=0;r<8;r++) s[r] = 0.0f;                                         \
    _Pragma("unroll 4")                                                       \
    for(int k=lane;k<2048;k+=64){                                             \
      const float4 pt = sPT[k];                                               \
      const float wk = sL[k];                                                 \
      _Pragma("unroll")                                                       \
      for(int r=0;r<8;r++)                                                    \
        s[r] += fexp2(fmaf(A[r].x,pt.x,fmaf(A[r].y,pt.y,                      \
                      fmaf(A[r].z,pt.z,wk))));                                \
    }                                                                         \
    _Pragma("unroll")                                                         \
    for(int r=0;r<8;r++) s[r] = wave_sum(s[r]);                               \
    if(lane==0){                                                              \
      _Pragma("unroll")                                                       \
      for(int r=0;r<8;r++)                                                    \
        st3(op+r0g+r, TAU*((ROWV?la[r]:lb2) - fmaf(sc,AR[r].w,flog2(s[r])))); \
    }                                                                         \
    bbar(bbase, PH, blk);                                                     \
  }

__global__ __launch_bounds__(256,2) void k_fused(const float* __restrict__ x0,
                                                 const float* __restrict__ xgt,
                                                 const float* __restrict__ vp,
                                                 const float* __restrict__ ap,
                                                 const float* __restrict__ mxp,
                                                 float* __restrict__ ws,
                                                 float* __restrict__ out){
  __shared__ float4 sA[2048];       // batch A points (raw -> scaled in place)
  __shared__ float4 sB[2048];       // batch B points (raw -> scaled in place)
  __shared__ float  sL[2048];       // per-pass folded k-constant
  __shared__ float  sa32[32], sla[32], sal[32];
  __shared__ float  sred[12];
  const int blk = blockIdx.x, tid = threadIdx.x, lane = tid&63, wid = tid>>6;
  const int b = blk>>6, j = blk&63;               // batch, block-in-batch
  const int r0l = j*32 + (wid<<3);                // batch-local row (8/wave)
  const int r0g = b*2048 + r0l;                   // global row
  unsigned* bbase = reinterpret_cast<unsigned*>(ws) + OFF_BBAR + b*512;
  unsigned* gb    = reinterpret_cast<unsigned*>(ws) + OFF_GBAR;

  // ---- local prep: load batch points raw, own-row alpha head ----
  for(int i=tid;i<2048;i+=256){
    const int gi = (b*2048 + i)*3;
    const float x = x0[gi], y = x0[gi+1], z = x0[gi+2];
    sA[i] = make_float4(x,y,z, x*x+y*y+z*z);
    const float gx = xgt[gi], gy = xgt[gi+1], gz = xgt[gi+2];
    sB[i] = make_float4(gx,gy,gz, gx*gx+gy*gy+gz*gz);
  }
  if(wid == 0){
    float a_=0.0f, w_=0.0f, se_=0.0f;
    if(lane < 32){
      const int row = b*2048 + j*32 + lane;
      const float al = ap[row];
      const float a = 1.0f/(1.0f + fexp2(-10.0f*tanhf(al*0.1f)*LOG2E));
      sa32[lane] = a;
      sla[lane]  = flog2(fmaxf(a,1e-30f));
      sal[lane]  = al;
      const float w = 1.0f/(1.0f + fexp2(-al*LOG2E));
      const float x = x0[row*3], y = x0[row*3+1], z = x0[row*3+2];
      const float tx = mxp[row*3]-x, ty = mxp[row*3+1]-y, tz = mxp[row*3+2]-z;
      const float dx = vp[row*3]-tx, dy = vp[row*3+1]-ty, dz = vp[row*3+2]-tz;
      a_ = a; w_ = w; se_ = (dx*dx+dy*dy+dz*dz)*w;
    }
    const float sa_s = wave_sum(a_), sw_s = wave_sum(w_), sew_s = wave_sum(se_);
    if(lane == 0){
      st3(ws+OFF_SUMAP+blk, sa_s);
      st3(ws+OFF_SWP  +blk, sw_s);
      st3(ws+OFF_SEWP +blk, sew_s);
    }
  }
  __syncthreads();

  // own-row fragments (RAW, persist across all passes) + alpha registers
  float4 AR[8], AC[8]; float la[8], av[8], alv[8];
  #pragma unroll
  for(int r=0;r<8;r++){
    AR[r] = sA[r0l+r]; AC[r] = sB[r0l+r];
    la[r] = sla[(wid<<3)+r]; av[r] = sa32[(wid<<3)+r]; alv[r] = sal[(wid<<3)+r];
  }

  // ---- phase 1: cmax (raw points) ----
  {
    float c[8];
    #pragma unroll
    for(int r=0;r<8;r++) c[r] = 0.0f;             // init 0 == clamp at 0
    #pragma unroll 4
    for(int k=lane;k<2048;k+=64){
      const float4 pt = sB[k];
      #pragma unroll
      for(int r=0;r<8;r++){
        const float d = AR[r].x*pt.x + AR[r].y*pt.y + AR[r].z*pt.z;
        c[r] = fmaxf(c[r], AR[r].w + pt.w - 2.0f*d);
      }
    }
    float cm8 = c[0];
    #pragma unroll
    for(int r=1;r<8;r++) cm8 = fmaxf(cm8, c[r]);
    const float cmv = wave_max(cm8);
    if(lane==0) sred[wid] = cmv;
    __syncthreads();
    if(tid==0){
      float m = sred[0];
      #pragma unroll
      for(int i=1;i<4;i++) m = fmaxf(m, sred[i]);
      st3(ws+OFF_CPART+blk, m);
    }
  }
  bbar(bbase, 1, blk);

  // ---- per-batch constants (lane indexes the batch's 64 block partials) ----
  const float cm = wave_max(ld3(ws+OFF_CPART + b*64 + lane));
  const float sc = NEG20LOG2E/(cm + 1e-8f);
  const float n2sc = -2.0f*sc;
  const float sav = wave_sum(ld3(ws+OFF_SUMAP + b*64 + lane));
  const float lb2 = flog2(fmaxf(sav*(1.0f/2048.0f), 1e-30f));

  // ---- rescale LDS points in place (pt = {n2sc*xyz, sc*|.|^2}) ----
  for(int i=tid;i<2048;i+=256){
    const float4 qa = sA[i];
    sA[i] = make_float4(n2sc*qa.x, n2sc*qa.y, n2sc*qa.z, sc*qa.w);
    const float4 qb = sB[i];
    sB[i] = make_float4(n2sc*qb.x, n2sc*qb.y, n2sc*qb.z, sc*qb.w);
  }
  __syncthreads();

  // ---- phases 2..11: 5 Sinkhorn iterations (row, col), per-batch sync ----
  LSE_PASS(true,  true,  2)
  LSE_PASS(false, false, 3)
  LSE_PASS(true,  false, 4)
  LSE_PASS(false, false, 5)
  LSE_PASS(true,  false, 6)
  LSE_PASS(false, false, 7)
  LSE_PASS(true,  false, 8)
  LSE_PASS(false, false, 9)
  LSE_PASS(true,  false, 10)
  LSE_PASS(false, false, 11)

  // ---- final pi pass (hoisted cr = sc|A|^2 + lu; per-row S,Q,L accums) ----
  {
    float* lv = ws + OFF_LV + 2048*b;
    for(int i=tid;i<2048;i+=256) sL[i] = ld3(lv+i);   // raw lv (L needs it)
    __syncthreads();
    float lus[8];
    #pragma unroll
    for(int r=0;r<8;r++) lus[r] = ld3(ws+OFF_LU+r0g+r);
    float S[8], Q[8], L[8];
    #pragma unroll
    for(int r=0;r<8;r++){ S[r]=0.0f; Q[r]=0.0f; L[r]=0.0f; }
    #pragma unroll 2
    for(int k=lane;k<2048;k+=64){
      const float4 pt = sB[k];
      const float lvk = sL[k];
      const float wk = pt.w + lvk;
      #pragma unroll
      for(int r=0;r<8;r++){
        const float c = fmaf(AR[r].x,pt.x,fmaf(AR[r].y,pt.y,
                        fmaf(AR[r].z,pt.z,wk)));
        const float p = fexp2(c);
        S[r] += p; Q[r] = fmaf(p,c,Q[r]); L[r] = fmaf(p,lvk,L[r]);
      }
    }
    #pragma unroll
    for(int r=0;r<8;r++){
      S[r]=wave_sum(S[r]); Q[r]=wave_sum(Q[r]); L[r]=wave_sum(L[r]);
    }
    float spc = 0.0f, bce = 0.0f, spt = 0.0f;
    #pragma unroll
    for(int r=0;r<8;r++){
      const float cr = fmaf(sc, AR[r].w, lus[r]);   // hoisted row constant
      const float p2 = fexp2(cr);
      const float sp = p2*S[r];                     // true row sum of pi
      // sum(pi*arg_true) = p2*(Q + cr*S); klog = arg_true - lu - lv
      spc += p2*fmaf(cr,S[r],Q[r]) - p2*L[r] - lus[r]*sp;
      float yv = sp / (av[r] + 1e-8f);
      yv = fminf(fmaxf(yv,0.0f),1.0f);
      const float al = alv[r];
      bce += fmaxf(al,0.0f) - al*yv
           + 0.69314718056f*flog2(1.0f + fexp2(-fabsf(al)*LOG2E));
      spt += sp;
    }
    if(lane==0){ sred[wid]=bce; sred[4+wid]=spt; sred[8+wid]=spc; }
    __syncthreads();
    if(tid==0){
      float tb=0, ts=0, tc=0;
      #pragma unroll
      for(int i=0;i<4;i++){ tb+=sred[i]; ts+=sred[4+i]; tc+=sred[8+i]; }
      st3(ws+OFF_FPART +        blk, tb);
      st3(ws+OFF_FPART + 512  + blk, ts);
      st3(ws+OFF_FPART + 1024 + blk, tc);
    }
  }
  gbar_all(gb, blk);

  // ---- combine (block 0 only, 256 threads over 512 partials) ----
  if(blk == 0){
    float pb = ld3(ws+OFF_FPART+tid)      + ld3(ws+OFF_FPART+tid+256);
    float ps = ld3(ws+OFF_FPART+512+tid)  + ld3(ws+OFF_FPART+512+tid+256);
    float pc = ld3(ws+OFF_FPART+1024+tid) + ld3(ws+OFF_FPART+1024+tid+256);
    float pw = ld3(ws+OFF_SWP+tid)        + ld3(ws+OFF_SWP+tid+256);
    float pe = ld3(ws+OFF_SEWP+tid)       + ld3(ws+OFF_SEWP+tid+256);
    pb=wave_sum(pb); ps=wave_sum(ps); pc=wave_sum(pc);
    pw=wave_sum(pw); pe=wave_sum(pe);
    if(lane==0){
      sL[wid*5+0]=pb; sL[wid*5+1]=ps; sL[wid*5+2]=pc;
      sL[wid*5+3]=pw; sL[wid*5+4]=pe;
    }
    __syncthreads();
    if(tid==0){
      float bce=0, sp=0, spc=0, sw=0, sew=0;
      #pragma unroll
      for(int w=0;w<4;w++){
        bce+=sL[w*5+0]; sp+=sL[w*5+1]; spc+=sL[w*5+2];
        sw +=sL[w*5+3]; sew+=sL[w*5+4];
      }
      const float loss_vel  = sew / fmaxf(sw, 1.0f);
      const float loss_surv = bce / 16384.0f;
      // sum(pi*cost_n) = spc * (-ln2/20)  since klog = -20*log2e*cost_n
      const float loss_tr = (spc * (-0.03465735902799726f)) / fmaxf(sp, 1e-8f);
      out[0] = loss_vel + loss_surv + 0.1f*loss_tr;
    }
  }
}

extern "C" void kernel_launch(void* const* d_in, const int* in_sizes, int n_in,
                              void* d_out, int out_size, void* d_ws, size_t ws_size,
                              hipStream_t stream) {
  (void)in_sizes; (void)n_in; (void)out_size; (void)ws_size;
  const float* x0  = (const float*)d_in[0];
  const float* xgt = (const float*)d_in[1];
  const float* vp  = (const float*)d_in[2];
  const float* ap  = (const float*)d_in[3];
  const float* mxp = (const float*)d_in[5];   // t (d_in[4]) unused
  float* ws  = (float*)d_ws;
  float* out = (float*)d_out;

  k_init<<<1, 256, 0, stream>>>(ws);          // zero all barrier words

  k_fused<<<512, 256, 0, stream>>>(x0, xgt, vp, ap, mxp, ws, out);
}